// Round 4
// baseline (445.420 us; speedup 1.0000x reference)
//
#include <hip/hip_runtime.h>

#define N_NODES 50000
#define N_EDGES 800000
#define D 128
#define N4 (N_NODES / 4)               // 12500 int4 groups
#define NBLK_SCAN ((N4 + 255) / 256)   // 49

// -------- workspace layout (element offsets) --------
#define H1_OFF   0
#define INVD_OFF (N_NODES * D)
#define WT1_OFF  (INVD_OFF + N_NODES)
#define WT2_OFF  (WT1_OFF + D * D)
#define INT_OFF  (WT2_OFF + D * D)
// ints (relative to int base): row_start[50001]→pad 50004 | cursor[50000] | csr_src[800000] | blocksum[64]
#define RS_OFF   0
#define CUR_OFF  50004
#define CSR_OFF  (CUR_OFF + N_NODES)
#define BS_OFF   (CSR_OFF + N_EDGES)

// ---------------- transpose W (both layers in one launch) ----------------
__global__ void transpose2_kernel(const float* __restrict__ W1, const float* __restrict__ W2,
                                  float* __restrict__ Wt1, float* __restrict__ Wt2) {
    int idx = blockIdx.x * 256 + threadIdx.x;     // 0..32767
    const float* W = (idx < D * D) ? W1 : W2;
    float* Wt      = (idx < D * D) ? Wt1 : Wt2;
    int i = idx & (D * D - 1);
    int j = i >> 7;
    int k = i & 127;
    Wt[k * D + j] = W[j * D + k];
}

// ---------------- CSR build ----------------
__global__ void count_kernel(const int* __restrict__ dst, int* __restrict__ cnt) {
    int e = blockIdx.x * blockDim.x + threadIdx.x;
    if (e < N_EDGES) atomicAdd(&cnt[dst[e]], 1);
}

__global__ __launch_bounds__(256) void partial_kernel(const int* __restrict__ cnt,
                                                      int* __restrict__ blocksum) {
    __shared__ int red[4];
    int t = threadIdx.x;
    int i4 = blockIdx.x * 256 + t;
    int s = 0;
    if (i4 < N4) {
        int4 v = ((const int4*)cnt)[i4];
        s = v.x + v.y + v.z + v.w;
    }
#pragma unroll
    for (int off = 1; off < 64; off <<= 1) s += __shfl_xor(s, off, 64);
    if ((t & 63) == 0) red[t >> 6] = s;
    __syncthreads();
    if (t == 0) blocksum[blockIdx.x] = red[0] + red[1] + red[2] + red[3];
}

__global__ __launch_bounds__(64) void scanblk_kernel(int* __restrict__ blocksum) {
    __shared__ int buf[64];
    int t = threadIdx.x;
    int v = (t < NBLK_SCAN) ? blocksum[t] : 0;
    buf[t] = v;
    __syncthreads();
#pragma unroll
    for (int off = 1; off < 64; off <<= 1) {
        int a = (t >= off) ? buf[t - off] : 0;
        __syncthreads();
        buf[t] += a;
        __syncthreads();
    }
    if (t < NBLK_SCAN) blocksum[t] = buf[t] - v;
}

__global__ __launch_bounds__(256) void write_kernel(int* __restrict__ cnt_cursor,
                                                    const int* __restrict__ blocksum,
                                                    int* __restrict__ row_start,
                                                    float* __restrict__ invd) {
    __shared__ int tsum[256];
    int t = threadIdx.x;
    int i4 = blockIdx.x * 256 + t;
    int4 v = make_int4(0, 0, 0, 0);
    bool act = (i4 < N4);
    if (act) v = ((const int4*)cnt_cursor)[i4];
    int s = v.x + v.y + v.z + v.w;
    tsum[t] = s;
    __syncthreads();
#pragma unroll
    for (int off = 1; off < 256; off <<= 1) {
        int a = (t >= off) ? tsum[t - off] : 0;
        __syncthreads();
        tsum[t] += a;
        __syncthreads();
    }
    int excl = blocksum[blockIdx.x] + tsum[t] - s;
    if (act) {
        int4 rs;
        rs.x = excl;
        rs.y = rs.x + v.x;
        rs.z = rs.y + v.y;
        rs.w = rs.z + v.z;
        ((int4*)row_start)[i4] = rs;
        ((int4*)cnt_cursor)[i4] = rs;
        int i = i4 * 4;
        invd[i + 0] = 1.0f / (float)(v.x + 1);
        invd[i + 1] = 1.0f / (float)(v.y + 1);
        invd[i + 2] = 1.0f / (float)(v.z + 1);
        invd[i + 3] = 1.0f / (float)(v.w + 1);
    }
    if (i4 == 0) row_start[N_NODES] = N_EDGES;
}

__global__ void fill_kernel(const int* __restrict__ src, const int* __restrict__ dst,
                            int* __restrict__ cursor, int* __restrict__ csr_src) {
    int e = blockIdx.x * blockDim.x + threadIdx.x;
    if (e < N_EDGES) {
        int d = dst[e];
        int pos = atomicAdd(&cursor[d], 1);
        csr_src[pos] = src[e];
    }
}

// ---------------- fused gather-aggregate + normalize + GEMM ----------------
// LDS: xl only (16.9 KB) -> 6-8 blocks/CU. W read from global (L1/L2-hot,
// identical addresses across waves). Phase B: thread = 4 cols x 4 node-rows.
template <int RELU>
__global__ __launch_bounds__(256, 6) void sage_fused_kernel(const float* __restrict__ x,
                                                            const int* __restrict__ row_start,
                                                            const int* __restrict__ csr_src,
                                                            const float* __restrict__ invd,
                                                            const float* __restrict__ Wt,
                                                            const float* __restrict__ bias,
                                                            float* __restrict__ out) {
    __shared__ float xl[32 * 132];   // 32 nodes x 128, stride 132
    const int t = threadIdx.x;
    const int n0 = blockIdx.x * 32;
    const int g = t >> 5;            // group 0..7
    const int c = t & 31;            // float4 column

    // Phase A: gather + aggregate 4 nodes per group (8-deep MLP)
#pragma unroll
    for (int q = 0; q < 4; ++q) {
        int n = g * 4 + q;
        int node = n0 + n;
        float4 acc = make_float4(0.f, 0.f, 0.f, 0.f);
        if (node < N_NODES) {
            acc = ((const float4*)x)[(size_t)node * 32 + c];   // self
            int e0 = row_start[node];
            int e1 = row_start[node + 1];
            int e = e0;
            int nb = e0 + ((e1 - e0) & ~7);
            for (; e < nb; e += 8) {
                int s0 = csr_src[e + 0];
                int s1 = csr_src[e + 1];
                int s2 = csr_src[e + 2];
                int s3 = csr_src[e + 3];
                int s4 = csr_src[e + 4];
                int s5 = csr_src[e + 5];
                int s6 = csr_src[e + 6];
                int s7 = csr_src[e + 7];
                float4 v0 = ((const float4*)x)[(size_t)s0 * 32 + c];
                float4 v1 = ((const float4*)x)[(size_t)s1 * 32 + c];
                float4 v2 = ((const float4*)x)[(size_t)s2 * 32 + c];
                float4 v3 = ((const float4*)x)[(size_t)s3 * 32 + c];
                float4 v4 = ((const float4*)x)[(size_t)s4 * 32 + c];
                float4 v5 = ((const float4*)x)[(size_t)s5 * 32 + c];
                float4 v6 = ((const float4*)x)[(size_t)s6 * 32 + c];
                float4 v7 = ((const float4*)x)[(size_t)s7 * 32 + c];
                acc.x += ((v0.x + v1.x) + (v2.x + v3.x)) + ((v4.x + v5.x) + (v6.x + v7.x));
                acc.y += ((v0.y + v1.y) + (v2.y + v3.y)) + ((v4.y + v5.y) + (v6.y + v7.y));
                acc.z += ((v0.z + v1.z) + (v2.z + v3.z)) + ((v4.z + v5.z) + (v6.z + v7.z));
                acc.w += ((v0.w + v1.w) + (v2.w + v3.w)) + ((v4.w + v5.w) + (v6.w + v7.w));
            }
            if (e1 - e >= 4) {
                int s0 = csr_src[e + 0];
                int s1 = csr_src[e + 1];
                int s2 = csr_src[e + 2];
                int s3 = csr_src[e + 3];
                float4 v0 = ((const float4*)x)[(size_t)s0 * 32 + c];
                float4 v1 = ((const float4*)x)[(size_t)s1 * 32 + c];
                float4 v2 = ((const float4*)x)[(size_t)s2 * 32 + c];
                float4 v3 = ((const float4*)x)[(size_t)s3 * 32 + c];
                acc.x += (v0.x + v1.x) + (v2.x + v3.x);
                acc.y += (v0.y + v1.y) + (v2.y + v3.y);
                acc.z += (v0.z + v1.z) + (v2.z + v3.z);
                acc.w += (v0.w + v1.w) + (v2.w + v3.w);
                e += 4;
            }
            for (; e < e1; ++e) {
                int s = csr_src[e];
                float4 v = ((const float4*)x)[(size_t)s * 32 + c];
                acc.x += v.x; acc.y += v.y; acc.z += v.z; acc.w += v.w;
            }
            float iv = invd[node];
            acc.x *= iv; acc.y *= iv; acc.z *= iv; acc.w *= iv;
        }
        *(float4*)(&xl[n * 132 + c * 4]) = acc;
    }

    __syncthreads();

    // Phase B: GEMM. j = col-group (4 cols), rows r, r+8, r+16, r+24.
    const int j = t & 31;
    const int r = t >> 5;
    const float4* wt4 = (const float4*)Wt;

    float4 bv = ((const float4*)bias)[j];
    float4 acc[4];
#pragma unroll
    for (int m = 0; m < 4; ++m) acc[m] = bv;

    for (int k = 0; k < 128; k += 4) {
        float4 w0 = wt4[(k + 0) * 32 + j];
        float4 w1 = wt4[(k + 1) * 32 + j];
        float4 w2 = wt4[(k + 2) * 32 + j];
        float4 w3 = wt4[(k + 3) * 32 + j];
#pragma unroll
        for (int m = 0; m < 4; ++m) {
            float4 xv = *(const float4*)(&xl[(r + 8 * m) * 132 + k]);
            acc[m].x += xv.x * w0.x + xv.y * w1.x + xv.z * w2.x + xv.w * w3.x;
            acc[m].y += xv.x * w0.y + xv.y * w1.y + xv.z * w2.y + xv.w * w3.y;
            acc[m].z += xv.x * w0.z + xv.y * w1.z + xv.z * w2.z + xv.w * w3.z;
            acc[m].w += xv.x * w0.w + xv.y * w1.w + xv.z * w2.w + xv.w * w3.w;
        }
    }

#pragma unroll
    for (int m = 0; m < 4; ++m) {
        int node = n0 + r + 8 * m;
        if (node >= N_NODES) continue;
        float4 o = acc[m];
        if (RELU) {
            o.x = fmaxf(o.x, 0.f);
            o.y = fmaxf(o.y, 0.f);
            o.z = fmaxf(o.z, 0.f);
            o.w = fmaxf(o.w, 0.f);
        }
        ((float4*)out)[(size_t)node * 32 + j] = o;
    }
}

extern "C" void kernel_launch(void* const* d_in, const int* in_sizes, int n_in,
                              void* d_out, int out_size, void* d_ws, size_t ws_size,
                              hipStream_t stream) {
    const float* h  = (const float*)d_in[0];
    const int*   ei = (const int*)d_in[1];
    const float* W1 = (const float*)d_in[2];
    const float* b1 = (const float*)d_in[3];
    const float* W2 = (const float*)d_in[4];
    const float* b2 = (const float*)d_in[5];
    float* out = (float*)d_out;
    float* ws  = (float*)d_ws;

    float* h1   = ws + H1_OFF;
    float* invd = ws + INVD_OFF;
    float* Wt1  = ws + WT1_OFF;
    float* Wt2  = ws + WT2_OFF;
    int* ints      = (int*)(ws + INT_OFF);
    int* row_start = ints + RS_OFF;
    int* cursor    = ints + CUR_OFF;
    int* csr_src   = ints + CSR_OFF;
    int* blocksum  = ints + BS_OFF;

    const int* src = ei;
    const int* dst = ei + N_EDGES;

    hipMemsetAsync(cursor, 0, (size_t)N_NODES * sizeof(int), stream);

    transpose2_kernel<<<128, 256, 0, stream>>>(W1, W2, Wt1, Wt2);
    count_kernel<<<(N_EDGES + 255) / 256, 256, 0, stream>>>(dst, cursor);
    partial_kernel<<<NBLK_SCAN, 256, 0, stream>>>(cursor, blocksum);
    scanblk_kernel<<<1, 64, 0, stream>>>(blocksum);
    write_kernel<<<NBLK_SCAN, 256, 0, stream>>>(cursor, blocksum, row_start, invd);
    fill_kernel<<<(N_EDGES + 255) / 256, 256, 0, stream>>>(src, dst, cursor, csr_src);

    // layer 1: h -> h1 (ReLU)
    sage_fused_kernel<1><<<(N_NODES + 31) / 32, 256, 0, stream>>>(h, row_start, csr_src, invd, Wt1, b1, h1);
    // layer 2: h1 -> out
    sage_fused_kernel<0><<<(N_NODES + 31) / 32, 256, 0, stream>>>(h1, row_start, csr_src, invd, Wt2, b2, out);
}

// Round 5
// 329.207 us; speedup vs baseline: 1.3530x; 1.3530x over previous
//
#include <hip/hip_runtime.h>

#define N_NODES 50000
#define N_EDGES 800000
#define D 128
#define N4 (N_NODES / 4)               // 12500 int4 groups
#define NBLK_SCAN ((N4 + 255) / 256)   // 49

// -------- workspace layout (element offsets) --------
// floats: xn[6,400,000] | invd[50,000] | Wt1[16,384] | Wt2[16,384] | int region
// h1 lives in d_out (dead before gemm2 overwrites it).
#define XN_OFF   0
#define INVD_OFF (N_NODES * D)
#define WT1_OFF  (INVD_OFF + N_NODES)
#define WT2_OFF  (WT1_OFF + D * D)
#define INT_OFF  (WT2_OFF + D * D)
// ints (relative to int base): row_start[50001]→pad 50004 | cursor[50000] | csr_src[800000] | blocksum[64]
#define RS_OFF   0
#define CUR_OFF  50004
#define CSR_OFF  (CUR_OFF + N_NODES)
#define BS_OFF   (CSR_OFF + N_EDGES)

// ---------------- transpose W (both layers in one launch) ----------------
__global__ void transpose2_kernel(const float* __restrict__ W1, const float* __restrict__ W2,
                                  float* __restrict__ Wt1, float* __restrict__ Wt2) {
    int idx = blockIdx.x * 256 + threadIdx.x;     // 0..32767
    const float* W = (idx < D * D) ? W1 : W2;
    float* Wt      = (idx < D * D) ? Wt1 : Wt2;
    int i = idx & (D * D - 1);
    int j = i >> 7;
    int k = i & 127;
    Wt[k * D + j] = W[j * D + k];
}

// ---------------- CSR build ----------------
__global__ __launch_bounds__(256) void count_kernel(const int* __restrict__ dst, int* __restrict__ cnt) {
    int i = blockIdx.x * 256 + threadIdx.x;
    if (i < N_EDGES / 4) {
        int4 d = ((const int4*)dst)[i];
        atomicAdd(&cnt[d.x], 1);
        atomicAdd(&cnt[d.y], 1);
        atomicAdd(&cnt[d.z], 1);
        atomicAdd(&cnt[d.w], 1);
    }
}

__global__ __launch_bounds__(256) void partial_kernel(const int* __restrict__ cnt,
                                                      int* __restrict__ blocksum) {
    __shared__ int red[4];
    int t = threadIdx.x;
    int i4 = blockIdx.x * 256 + t;
    int s = 0;
    if (i4 < N4) {
        int4 v = ((const int4*)cnt)[i4];
        s = v.x + v.y + v.z + v.w;
    }
#pragma unroll
    for (int off = 1; off < 64; off <<= 1) s += __shfl_xor(s, off, 64);
    if ((t & 63) == 0) red[t >> 6] = s;
    __syncthreads();
    if (t == 0) blocksum[blockIdx.x] = red[0] + red[1] + red[2] + red[3];
}

__global__ __launch_bounds__(64) void scanblk_kernel(int* __restrict__ blocksum) {
    __shared__ int buf[64];
    int t = threadIdx.x;
    int v = (t < NBLK_SCAN) ? blocksum[t] : 0;
    buf[t] = v;
    __syncthreads();
#pragma unroll
    for (int off = 1; off < 64; off <<= 1) {
        int a = (t >= off) ? buf[t - off] : 0;
        __syncthreads();
        buf[t] += a;
        __syncthreads();
    }
    if (t < NBLK_SCAN) blocksum[t] = buf[t] - v;
}

__global__ __launch_bounds__(256) void write_kernel(int* __restrict__ cnt_cursor,
                                                    const int* __restrict__ blocksum,
                                                    int* __restrict__ row_start,
                                                    float* __restrict__ invd) {
    __shared__ int tsum[256];
    int t = threadIdx.x;
    int i4 = blockIdx.x * 256 + t;
    int4 v = make_int4(0, 0, 0, 0);
    bool act = (i4 < N4);
    if (act) v = ((const int4*)cnt_cursor)[i4];
    int s = v.x + v.y + v.z + v.w;
    tsum[t] = s;
    __syncthreads();
#pragma unroll
    for (int off = 1; off < 256; off <<= 1) {
        int a = (t >= off) ? tsum[t - off] : 0;
        __syncthreads();
        tsum[t] += a;
        __syncthreads();
    }
    int excl = blocksum[blockIdx.x] + tsum[t] - s;
    if (act) {
        int4 rs;
        rs.x = excl;
        rs.y = rs.x + v.x;
        rs.z = rs.y + v.y;
        rs.w = rs.z + v.z;
        ((int4*)row_start)[i4] = rs;
        ((int4*)cnt_cursor)[i4] = rs;
        int i = i4 * 4;
        invd[i + 0] = 1.0f / (float)(v.x + 1);
        invd[i + 1] = 1.0f / (float)(v.y + 1);
        invd[i + 2] = 1.0f / (float)(v.z + 1);
        invd[i + 3] = 1.0f / (float)(v.w + 1);
    }
    if (i4 == 0) row_start[N_NODES] = N_EDGES;
}

__global__ __launch_bounds__(256) void fill_kernel(const int* __restrict__ src, const int* __restrict__ dst,
                                                   int* __restrict__ cursor, int* __restrict__ csr_src) {
    int i = blockIdx.x * 256 + threadIdx.x;
    if (i < N_EDGES / 4) {
        int4 s4 = ((const int4*)src)[i];
        int4 d4 = ((const int4*)dst)[i];
        int p;
        p = atomicAdd(&cursor[d4.x], 1); csr_src[p] = s4.x;
        p = atomicAdd(&cursor[d4.y], 1); csr_src[p] = s4.y;
        p = atomicAdd(&cursor[d4.z], 1); csr_src[p] = s4.z;
        p = atomicAdd(&cursor[d4.w], 1); csr_src[p] = s4.w;
    }
}

// ---------------- gather + aggregate + normalize (no LDS, high occupancy) ----------------
__global__ __launch_bounds__(256, 6) void gather_kernel(const float* __restrict__ x,
                                                        const int* __restrict__ row_start,
                                                        const int* __restrict__ csr_src,
                                                        const float* __restrict__ invd,
                                                        float* __restrict__ xn) {
    const int t = threadIdx.x;
    const int n0 = blockIdx.x * 32;
    const int g = t >> 5;            // group 0..7
    const int c = t & 31;            // float4 column

#pragma unroll
    for (int q = 0; q < 4; ++q) {
        int node = n0 + g * 4 + q;
        if (node >= N_NODES) return;
        float4 acc = ((const float4*)x)[(size_t)node * 32 + c];   // self
        int e0 = row_start[node];
        int e1 = row_start[node + 1];
        int e = e0;
        int nb = e0 + ((e1 - e0) & ~7);
        for (; e < nb; e += 8) {
            int s0 = csr_src[e + 0];
            int s1 = csr_src[e + 1];
            int s2 = csr_src[e + 2];
            int s3 = csr_src[e + 3];
            int s4 = csr_src[e + 4];
            int s5 = csr_src[e + 5];
            int s6 = csr_src[e + 6];
            int s7 = csr_src[e + 7];
            float4 v0 = ((const float4*)x)[(size_t)s0 * 32 + c];
            float4 v1 = ((const float4*)x)[(size_t)s1 * 32 + c];
            float4 v2 = ((const float4*)x)[(size_t)s2 * 32 + c];
            float4 v3 = ((const float4*)x)[(size_t)s3 * 32 + c];
            float4 v4 = ((const float4*)x)[(size_t)s4 * 32 + c];
            float4 v5 = ((const float4*)x)[(size_t)s5 * 32 + c];
            float4 v6 = ((const float4*)x)[(size_t)s6 * 32 + c];
            float4 v7 = ((const float4*)x)[(size_t)s7 * 32 + c];
            acc.x += ((v0.x + v1.x) + (v2.x + v3.x)) + ((v4.x + v5.x) + (v6.x + v7.x));
            acc.y += ((v0.y + v1.y) + (v2.y + v3.y)) + ((v4.y + v5.y) + (v6.y + v7.y));
            acc.z += ((v0.z + v1.z) + (v2.z + v3.z)) + ((v4.z + v5.z) + (v6.z + v7.z));
            acc.w += ((v0.w + v1.w) + (v2.w + v3.w)) + ((v4.w + v5.w) + (v6.w + v7.w));
        }
        if (e1 - e >= 4) {
            int s0 = csr_src[e + 0];
            int s1 = csr_src[e + 1];
            int s2 = csr_src[e + 2];
            int s3 = csr_src[e + 3];
            float4 v0 = ((const float4*)x)[(size_t)s0 * 32 + c];
            float4 v1 = ((const float4*)x)[(size_t)s1 * 32 + c];
            float4 v2 = ((const float4*)x)[(size_t)s2 * 32 + c];
            float4 v3 = ((const float4*)x)[(size_t)s3 * 32 + c];
            acc.x += (v0.x + v1.x) + (v2.x + v3.x);
            acc.y += (v0.y + v1.y) + (v2.y + v3.y);
            acc.z += (v0.z + v1.z) + (v2.z + v3.z);
            acc.w += (v0.w + v1.w) + (v2.w + v3.w);
            e += 4;
        }
        for (; e < e1; ++e) {
            int s = csr_src[e];
            float4 v = ((const float4*)x)[(size_t)s * 32 + c];
            acc.x += v.x; acc.y += v.y; acc.z += v.z; acc.w += v.w;
        }
        float iv = invd[node];
        acc.x *= iv; acc.y *= iv; acc.z *= iv; acc.w *= iv;
        ((float4*)xn)[(size_t)node * 32 + c] = acc;
    }
}

// ---------------- GEMM: out = xn @ Wt (+bias, optional ReLU) ----------------
// 64-node x 128-col tile; xl (64x132 f32) + wl col-half (128x64 f32) in LDS.
template <int RELU>
__global__ __launch_bounds__(256, 2) void gemm_kernel(const float* __restrict__ xn,
                                                      const float* __restrict__ Wt,
                                                      const float* __restrict__ bias,
                                                      float* __restrict__ out) {
    __shared__ float xl[64 * 132];
    __shared__ float wl[128 * 64];
    const int t = threadIdx.x;
    const int n0 = blockIdx.x * 64;

    // stage xl: 2048 float4, 8 per thread
#pragma unroll
    for (int i = 0; i < 8; ++i) {
        int idx = t + i * 256;
        int n = idx >> 5;
        int c = idx & 31;
        int node = n0 + n;
        float4 v = make_float4(0.f, 0.f, 0.f, 0.f);
        if (node < N_NODES) v = ((const float4*)xn)[(size_t)node * 32 + c];
        *(float4*)(&xl[n * 132 + c * 4]) = v;
    }

    const int j = t & 15;    // col-group within 64-col half
    const int nr = t >> 4;   // rows nr, nr+16, nr+32, nr+48

#pragma unroll
    for (int h = 0; h < 2; ++h) {
        __syncthreads();   // xl ready (h=0) / previous-half wl readers done (h=1)
#pragma unroll
        for (int i = 0; i < 8; ++i) {
            int idx = t + i * 256;     // 2048 float4
            int k = idx >> 4;
            int cc = idx & 15;
            *(float4*)(&wl[k * 64 + cc * 4]) = ((const float4*)Wt)[k * 32 + h * 16 + cc];
        }
        __syncthreads();

        float4 bv = *(const float4*)(&bias[h * 64 + j * 4]);
        float4 acc[4];
#pragma unroll
        for (int m = 0; m < 4; ++m) acc[m] = bv;

        for (int k = 0; k < 128; k += 4) {
            float4 w0 = *(const float4*)(&wl[(k + 0) * 64 + j * 4]);
            float4 w1 = *(const float4*)(&wl[(k + 1) * 64 + j * 4]);
            float4 w2 = *(const float4*)(&wl[(k + 2) * 64 + j * 4]);
            float4 w3 = *(const float4*)(&wl[(k + 3) * 64 + j * 4]);
#pragma unroll
            for (int m = 0; m < 4; ++m) {
                float4 xv = *(const float4*)(&xl[(nr + 16 * m) * 132 + k]);
                acc[m].x += xv.x * w0.x + xv.y * w1.x + xv.z * w2.x + xv.w * w3.x;
                acc[m].y += xv.x * w0.y + xv.y * w1.y + xv.z * w2.y + xv.w * w3.y;
                acc[m].z += xv.x * w0.z + xv.y * w1.z + xv.z * w2.z + xv.w * w3.z;
                acc[m].w += xv.x * w0.w + xv.y * w1.w + xv.z * w2.w + xv.w * w3.w;
            }
        }

#pragma unroll
        for (int m = 0; m < 4; ++m) {
            int node = n0 + nr + 16 * m;
            if (node >= N_NODES) continue;
            float4 o = acc[m];
            if (RELU) {
                o.x = fmaxf(o.x, 0.f);
                o.y = fmaxf(o.y, 0.f);
                o.z = fmaxf(o.z, 0.f);
                o.w = fmaxf(o.w, 0.f);
            }
            ((float4*)out)[(size_t)node * 32 + h * 16 + j] = o;
        }
    }
}

extern "C" void kernel_launch(void* const* d_in, const int* in_sizes, int n_in,
                              void* d_out, int out_size, void* d_ws, size_t ws_size,
                              hipStream_t stream) {
    const float* h  = (const float*)d_in[0];
    const int*   ei = (const int*)d_in[1];
    const float* W1 = (const float*)d_in[2];
    const float* b1 = (const float*)d_in[3];
    const float* W2 = (const float*)d_in[4];
    const float* b2 = (const float*)d_in[5];
    float* out = (float*)d_out;
    float* ws  = (float*)d_ws;

    float* xn   = ws + XN_OFF;
    float* invd = ws + INVD_OFF;
    float* Wt1  = ws + WT1_OFF;
    float* Wt2  = ws + WT2_OFF;
    int* ints      = (int*)(ws + INT_OFF);
    int* row_start = ints + RS_OFF;
    int* cursor    = ints + CUR_OFF;
    int* csr_src   = ints + CSR_OFF;
    int* blocksum  = ints + BS_OFF;

    const int* src = ei;
    const int* dst = ei + N_EDGES;

    hipMemsetAsync(cursor, 0, (size_t)N_NODES * sizeof(int), stream);

    transpose2_kernel<<<128, 256, 0, stream>>>(W1, W2, Wt1, Wt2);
    count_kernel<<<(N_EDGES / 4 + 255) / 256, 256, 0, stream>>>(dst, cursor);
    partial_kernel<<<NBLK_SCAN, 256, 0, stream>>>(cursor, blocksum);
    scanblk_kernel<<<1, 64, 0, stream>>>(blocksum);
    write_kernel<<<NBLK_SCAN, 256, 0, stream>>>(cursor, blocksum, row_start, invd);
    fill_kernel<<<(N_EDGES / 4 + 255) / 256, 256, 0, stream>>>(src, dst, cursor, csr_src);

    // layer 1: h --gather--> xn --gemm+ReLU--> d_out (=h1)
    gather_kernel<<<(N_NODES + 31) / 32, 256, 0, stream>>>(h, row_start, csr_src, invd, xn);
    gemm_kernel<1><<<(N_NODES + 63) / 64, 256, 0, stream>>>(xn, Wt1, b1, out);

    // layer 2: d_out (=h1) --gather--> xn --gemm--> d_out
    gather_kernel<<<(N_NODES + 31) / 32, 256, 0, stream>>>(out, row_start, csr_src, invd, xn);
    gemm_kernel<0><<<(N_NODES + 63) / 64, 256, 0, stream>>>(xn, Wt2, b2, out);
}

// Round 6
// 287.515 us; speedup vs baseline: 1.5492x; 1.1450x over previous
//
#include <hip/hip_runtime.h>

#define N_NODES 50000
#define N_EDGES 800000
#define D 128
#define N4 (N_NODES / 4)               // 12500 int4 groups
#define NBLK_SCAN ((N4 + 255) / 256)   // 49

// -------- workspace layout (element offsets) --------
// floats: h1[6,400,000] | invd[50,000] | Wt1[16,384] | Wt2[16,384] | int region
#define H1_OFF   0
#define INVD_OFF (N_NODES * D)
#define WT1_OFF  (INVD_OFF + N_NODES)
#define WT2_OFF  (WT1_OFF + D * D)
#define INT_OFF  (WT2_OFF + D * D)
// ints (relative to int base): row_start[50001]→pad 50004 | cursor[50000] | csr_src[800000] | blocksum[64]
#define RS_OFF   0
#define CUR_OFF  50004
#define CSR_OFF  (CUR_OFF + N_NODES)
#define BS_OFF   (CSR_OFF + N_EDGES)

// ---------------- init: zero cursor + transpose both W ----------------
__global__ __launch_bounds__(256) void init_kernel(const float* __restrict__ W1,
                                                   const float* __restrict__ W2,
                                                   float* __restrict__ Wt1,
                                                   float* __restrict__ Wt2,
                                                   int* __restrict__ cursor) {
    int idx = blockIdx.x * 256 + threadIdx.x;
    if (idx < N4) {
        ((int4*)cursor)[idx] = make_int4(0, 0, 0, 0);
    } else {
        int i = idx - N4;
        if (i < 2 * D * D) {
            const float* W = (i < D * D) ? W1 : W2;
            float* Wt      = (i < D * D) ? Wt1 : Wt2;
            int ii = i & (D * D - 1);
            int j = ii >> 7;
            int k = ii & 127;
            Wt[k * D + j] = W[j * D + k];
        }
    }
}

// ---------------- CSR build ----------------
__global__ __launch_bounds__(256) void count_kernel(const int* __restrict__ dst, int* __restrict__ cnt) {
    int i = blockIdx.x * 256 + threadIdx.x;
    if (i < N_EDGES / 4) {
        int4 d = ((const int4*)dst)[i];
        atomicAdd(&cnt[d.x], 1);
        atomicAdd(&cnt[d.y], 1);
        atomicAdd(&cnt[d.z], 1);
        atomicAdd(&cnt[d.w], 1);
    }
}

__global__ __launch_bounds__(256) void partial_kernel(const int* __restrict__ cnt,
                                                      int* __restrict__ blocksum) {
    __shared__ int red[4];
    int t = threadIdx.x;
    int i4 = blockIdx.x * 256 + t;
    int s = 0;
    if (i4 < N4) {
        int4 v = ((const int4*)cnt)[i4];
        s = v.x + v.y + v.z + v.w;
    }
#pragma unroll
    for (int off = 1; off < 64; off <<= 1) s += __shfl_xor(s, off, 64);
    if ((t & 63) == 0) red[t >> 6] = s;
    __syncthreads();
    if (t == 0) blocksum[blockIdx.x] = red[0] + red[1] + red[2] + red[3];
}

__global__ __launch_bounds__(64) void scanblk_kernel(int* __restrict__ blocksum) {
    __shared__ int buf[64];
    int t = threadIdx.x;
    int v = (t < NBLK_SCAN) ? blocksum[t] : 0;
    buf[t] = v;
    __syncthreads();
#pragma unroll
    for (int off = 1; off < 64; off <<= 1) {
        int a = (t >= off) ? buf[t - off] : 0;
        __syncthreads();
        buf[t] += a;
        __syncthreads();
    }
    if (t < NBLK_SCAN) blocksum[t] = buf[t] - v;
}

__global__ __launch_bounds__(256) void write_kernel(int* __restrict__ cnt_cursor,
                                                    const int* __restrict__ blocksum,
                                                    int* __restrict__ row_start,
                                                    float* __restrict__ invd) {
    __shared__ int tsum[256];
    int t = threadIdx.x;
    int i4 = blockIdx.x * 256 + t;
    int4 v = make_int4(0, 0, 0, 0);
    bool act = (i4 < N4);
    if (act) v = ((const int4*)cnt_cursor)[i4];
    int s = v.x + v.y + v.z + v.w;
    tsum[t] = s;
    __syncthreads();
#pragma unroll
    for (int off = 1; off < 256; off <<= 1) {
        int a = (t >= off) ? tsum[t - off] : 0;
        __syncthreads();
        tsum[t] += a;
        __syncthreads();
    }
    int excl = blocksum[blockIdx.x] + tsum[t] - s;
    if (act) {
        int4 rs;
        rs.x = excl;
        rs.y = rs.x + v.x;
        rs.z = rs.y + v.y;
        rs.w = rs.z + v.z;
        ((int4*)row_start)[i4] = rs;
        ((int4*)cnt_cursor)[i4] = rs;
        int i = i4 * 4;
        invd[i + 0] = 1.0f / (float)(v.x + 1);
        invd[i + 1] = 1.0f / (float)(v.y + 1);
        invd[i + 2] = 1.0f / (float)(v.z + 1);
        invd[i + 3] = 1.0f / (float)(v.w + 1);
    }
    if (i4 == 0) row_start[N_NODES] = N_EDGES;
}

__global__ __launch_bounds__(256) void fill_kernel(const int* __restrict__ src, const int* __restrict__ dst,
                                                   int* __restrict__ cursor, int* __restrict__ csr_src) {
    int i = blockIdx.x * 256 + threadIdx.x;
    if (i < N_EDGES / 4) {
        int4 s4 = ((const int4*)src)[i];
        int4 d4 = ((const int4*)dst)[i];
        int p;
        p = atomicAdd(&cursor[d4.x], 1); csr_src[p] = s4.x;
        p = atomicAdd(&cursor[d4.y], 1); csr_src[p] = s4.y;
        p = atomicAdd(&cursor[d4.z], 1); csr_src[p] = s4.z;
        p = atomicAdd(&cursor[d4.w], 1); csr_src[p] = s4.w;
    }
}

// ---------------- fused gather + normalize + GEMM (quarter-W tiles) ----------------
// LDS = xl (16.9 KB) + wl quarter (16 KB) = 32.9 KB -> 4 blocks/CU.
// GEMM runs in 4 col-phases of 32; wl re-staged (L2-hot) between phases.
template <int RELU>
__global__ __launch_bounds__(256, 4) void sage_fused_kernel(const float* __restrict__ x,
                                                            const int* __restrict__ row_start,
                                                            const int* __restrict__ csr_src,
                                                            const float* __restrict__ invd,
                                                            const float* __restrict__ Wt,
                                                            const float* __restrict__ bias,
                                                            float* __restrict__ out) {
    __shared__ float xl[32 * 132];   // 32 nodes x 128, stride 132
    __shared__ float wl[128 * 32];   // quarter of Wt: [k][jj], jj = 32 cols
    const int t = threadIdx.x;
    const int n0 = blockIdx.x * 32;
    const int g = t >> 5;            // group 0..7
    const int c = t & 31;            // float4 column

    // pre-stage wl phase 0 (cols 0..31); overlaps with gather, barrier after gather covers it
#pragma unroll
    for (int i = 0; i < 4; ++i) {
        int idx = t + i * 256;                 // float4 slot 0..1023
        int k = idx >> 3;
        int jj = idx & 7;
        ((float4*)wl)[idx] = ((const float4*)Wt)[k * 32 + jj];
    }

    // Phase A: gather + aggregate 4 nodes per group (8-deep MLP)
#pragma unroll
    for (int q = 0; q < 4; ++q) {
        int n = g * 4 + q;
        int node = n0 + n;
        float4 acc = make_float4(0.f, 0.f, 0.f, 0.f);
        if (node < N_NODES) {
            acc = ((const float4*)x)[(size_t)node * 32 + c];   // self
            int e0 = row_start[node];
            int e1 = row_start[node + 1];
            int e = e0;
            int nb = e0 + ((e1 - e0) & ~7);
            for (; e < nb; e += 8) {
                int s0 = csr_src[e + 0];
                int s1 = csr_src[e + 1];
                int s2 = csr_src[e + 2];
                int s3 = csr_src[e + 3];
                int s4 = csr_src[e + 4];
                int s5 = csr_src[e + 5];
                int s6 = csr_src[e + 6];
                int s7 = csr_src[e + 7];
                float4 v0 = ((const float4*)x)[(size_t)s0 * 32 + c];
                float4 v1 = ((const float4*)x)[(size_t)s1 * 32 + c];
                float4 v2 = ((const float4*)x)[(size_t)s2 * 32 + c];
                float4 v3 = ((const float4*)x)[(size_t)s3 * 32 + c];
                float4 v4 = ((const float4*)x)[(size_t)s4 * 32 + c];
                float4 v5 = ((const float4*)x)[(size_t)s5 * 32 + c];
                float4 v6 = ((const float4*)x)[(size_t)s6 * 32 + c];
                float4 v7 = ((const float4*)x)[(size_t)s7 * 32 + c];
                acc.x += ((v0.x + v1.x) + (v2.x + v3.x)) + ((v4.x + v5.x) + (v6.x + v7.x));
                acc.y += ((v0.y + v1.y) + (v2.y + v3.y)) + ((v4.y + v5.y) + (v6.y + v7.y));
                acc.z += ((v0.z + v1.z) + (v2.z + v3.z)) + ((v4.z + v5.z) + (v6.z + v7.z));
                acc.w += ((v0.w + v1.w) + (v2.w + v3.w)) + ((v4.w + v5.w) + (v6.w + v7.w));
            }
            if (e1 - e >= 4) {
                int s0 = csr_src[e + 0];
                int s1 = csr_src[e + 1];
                int s2 = csr_src[e + 2];
                int s3 = csr_src[e + 3];
                float4 v0 = ((const float4*)x)[(size_t)s0 * 32 + c];
                float4 v1 = ((const float4*)x)[(size_t)s1 * 32 + c];
                float4 v2 = ((const float4*)x)[(size_t)s2 * 32 + c];
                float4 v3 = ((const float4*)x)[(size_t)s3 * 32 + c];
                acc.x += (v0.x + v1.x) + (v2.x + v3.x);
                acc.y += (v0.y + v1.y) + (v2.y + v3.y);
                acc.z += (v0.z + v1.z) + (v2.z + v3.z);
                acc.w += (v0.w + v1.w) + (v2.w + v3.w);
                e += 4;
            }
            for (; e < e1; ++e) {
                int s = csr_src[e];
                float4 v = ((const float4*)x)[(size_t)s * 32 + c];
                acc.x += v.x; acc.y += v.y; acc.z += v.z; acc.w += v.w;
            }
            float iv = invd[node];
            acc.x *= iv; acc.y *= iv; acc.z *= iv; acc.w *= iv;
        }
        *(float4*)(&xl[n * 132 + c * 4]) = acc;
    }

    __syncthreads();   // xl + wl(phase 0) ready

    // Phase B: 4 col-phases. j2 = float4 col-group (0..7), nr = node row (0..31).
    const int j2 = t & 7;
    const int nr = t >> 3;
    const int node = n0 + nr;

#pragma unroll
    for (int p = 0; p < 4; ++p) {
        float4 a = ((const float4*)bias)[p * 8 + j2];
        for (int k = 0; k < 128; k += 4) {
            float4 xv = *(const float4*)(&xl[nr * 132 + k]);
            float4 wa = ((const float4*)wl)[(k + 0) * 8 + j2];
            float4 wb = ((const float4*)wl)[(k + 1) * 8 + j2];
            float4 wc = ((const float4*)wl)[(k + 2) * 8 + j2];
            float4 wd = ((const float4*)wl)[(k + 3) * 8 + j2];
            a.x += xv.x * wa.x + xv.y * wb.x + xv.z * wc.x + xv.w * wd.x;
            a.y += xv.x * wa.y + xv.y * wb.y + xv.z * wc.y + xv.w * wd.y;
            a.z += xv.x * wa.z + xv.y * wb.z + xv.z * wc.z + xv.w * wd.z;
            a.w += xv.x * wa.w + xv.y * wb.w + xv.z * wc.w + xv.w * wd.w;
        }
        if (RELU) {
            a.x = fmaxf(a.x, 0.f);
            a.y = fmaxf(a.y, 0.f);
            a.z = fmaxf(a.z, 0.f);
            a.w = fmaxf(a.w, 0.f);
        }
        if (node < N_NODES) ((float4*)out)[(size_t)node * 32 + p * 8 + j2] = a;

        if (p < 3) {
            __syncthreads();   // all readers done with wl
#pragma unroll
            for (int i = 0; i < 4; ++i) {
                int idx = t + i * 256;
                int k = idx >> 3;
                int jj = idx & 7;
                ((float4*)wl)[idx] = ((const float4*)Wt)[k * 32 + (p + 1) * 8 + jj];
            }
            __syncthreads();   // wl(p+1) ready
        }
    }
}

extern "C" void kernel_launch(void* const* d_in, const int* in_sizes, int n_in,
                              void* d_out, int out_size, void* d_ws, size_t ws_size,
                              hipStream_t stream) {
    const float* h  = (const float*)d_in[0];
    const int*   ei = (const int*)d_in[1];
    const float* W1 = (const float*)d_in[2];
    const float* b1 = (const float*)d_in[3];
    const float* W2 = (const float*)d_in[4];
    const float* b2 = (const float*)d_in[5];
    float* out = (float*)d_out;
    float* ws  = (float*)d_ws;

    float* h1   = ws + H1_OFF;
    float* invd = ws + INVD_OFF;
    float* Wt1  = ws + WT1_OFF;
    float* Wt2  = ws + WT2_OFF;
    int* ints      = (int*)(ws + INT_OFF);
    int* row_start = ints + RS_OFF;
    int* cursor    = ints + CUR_OFF;
    int* csr_src   = ints + CSR_OFF;
    int* blocksum  = ints + BS_OFF;

    const int* src = ei;
    const int* dst = ei + N_EDGES;

    init_kernel<<<(N4 + 2 * D * D + 255) / 256, 256, 0, stream>>>(W1, W2, Wt1, Wt2, cursor);
    count_kernel<<<(N_EDGES / 4 + 255) / 256, 256, 0, stream>>>(dst, cursor);
    partial_kernel<<<NBLK_SCAN, 256, 0, stream>>>(cursor, blocksum);
    scanblk_kernel<<<1, 64, 0, stream>>>(blocksum);
    write_kernel<<<NBLK_SCAN, 256, 0, stream>>>(cursor, blocksum, row_start, invd);
    fill_kernel<<<(N_EDGES / 4 + 255) / 256, 256, 0, stream>>>(src, dst, cursor, csr_src);

    // layer 1: h -> h1 (ReLU)
    sage_fused_kernel<1><<<(N_NODES + 31) / 32, 256, 0, stream>>>(h, row_start, csr_src, invd, Wt1, b1, h1);
    // layer 2: h1 -> out
    sage_fused_kernel<0><<<(N_NODES + 31) / 32, 256, 0, stream>>>(h1, row_start, csr_src, invd, Wt2, b2, out);
}